// Round 3
// baseline (360.706 us; speedup 1.0000x reference)
//
#include <hip/hip_runtime.h>
#include <math.h>

// Problem constants (match reference file)
#define N_Q  32768
#define LEN  2048
#define ROWS_PER_BLOCK 4   // 4 waves of 64 lanes per 256-thread block

// One wave per row. Each lane loads 8 x float4 (32 elements) of the row,
// finds the highest index j with t_pad[row][j] <= t[row] plus its value,
// then a wave-wide max-index pair reduction. Lane 0 writes
//   exp(-(t - t_last)) if any index qualified, else 0.
__global__ __launch_bounds__(256) void markov_last_event_kernel(
    const float* __restrict__ t,
    const float* __restrict__ t_pad,
    float* __restrict__ out)
{
    const int wave = threadIdx.x >> 6;   // 0..3
    const int lane = threadIdx.x & 63;   // 0..63
    const int row  = blockIdx.x * ROWS_PER_BLOCK + wave;

    const float tq = t[row];
    const float4* rp = reinterpret_cast<const float4*>(t_pad + (size_t)row * LEN);

    int   best_idx = -1;
    float best_val = 0.0f;

    // 8 chunks of 256 contiguous elements; lane reads float4 at (chunk*256 + lane*4).
    // Fully coalesced: within a chunk, lane i touches bytes [i*16, i*16+16).
    #pragma unroll
    for (int c = 0; c < 8; ++c) {
        const float4 v   = rp[c * 64 + lane];
        const int    eix = c * 256 + lane * 4;
        // Highest qualifying index within this float4; chunks increase in index,
        // so any hit in a later chunk legitimately overwrites an earlier one.
        if      (v.w <= tq) { best_idx = eix + 3; best_val = v.w; }
        else if (v.z <= tq) { best_idx = eix + 2; best_val = v.z; }
        else if (v.y <= tq) { best_idx = eix + 1; best_val = v.y; }
        else if (v.x <= tq) { best_idx = eix + 0; best_val = v.x; }
    }

    // Wave64 pair-reduction: keep the (idx, val) with the larger idx.
    #pragma unroll
    for (int off = 32; off > 0; off >>= 1) {
        const int   oi = __shfl_down(best_idx, off);
        const float ov = __shfl_down(best_val, off);
        if (oi > best_idx) { best_idx = oi; best_val = ov; }
    }

    if (lane == 0) {
        out[row] = (best_idx >= 0) ? expf(-(tq - best_val)) : 0.0f;
    }
}

extern "C" void kernel_launch(void* const* d_in, const int* in_sizes, int n_in,
                              void* d_out, int out_size, void* d_ws, size_t ws_size,
                              hipStream_t stream)
{
    // setup_inputs order: src(0), dst(1), t(2), x_pad_simu(3), t_pad(4).
    // Only t and t_pad feed the output.
    const float* t     = (const float*)d_in[2];
    const float* t_pad = (const float*)d_in[4];
    float*       out   = (float*)d_out;

    markov_last_event_kernel<<<dim3(N_Q / ROWS_PER_BLOCK), dim3(256), 0, stream>>>(
        t, t_pad, out);
}

// Round 4
// 311.224 us; speedup vs baseline: 1.1590x; 1.1590x over previous
//
#include <hip/hip_runtime.h>
#include <math.h>

// Problem constants (match reference file)
#define N_Q  32768
#define LEN  2048
#define ROWS_PER_BLOCK 4   // 4 waves of 64 lanes per 256-thread block

// Two-phase backward search, one wave (64 lanes) per row.
// Phase 1: probe the LAST 256 elements (1 float4/lane). For ~99.6% of rows
//   (P[miss] = E[(1-t)^256] = 1/257 for uniform data) the last qualifying
//   index lives here; the highest hit lane (via 64-bit ballot) holds it.
// Phase 2 (rare, wave-uniform branch): read the remaining 1792 elements with
//   7 independent float4 loads per lane and do a max-index shuffle reduction.
// Expected HBM traffic: ~33 MB instead of 256 MB for the full-read version.
__global__ __launch_bounds__(256) void markov_last_event_kernel(
    const float* __restrict__ t,
    const float* __restrict__ t_pad,
    float* __restrict__ out)
{
    const int wave = threadIdx.x >> 6;   // 0..3
    const int lane = threadIdx.x & 63;   // 0..63
    const int row  = blockIdx.x * ROWS_PER_BLOCK + wave;

    const float tq = t[row];
    const float4* rp = reinterpret_cast<const float4*>(t_pad + (size_t)row * LEN);

    // ---- Phase 1: last chunk (elements 1792..2047), coalesced 16B/lane ----
    {
        const float4 v = rp[7 * 64 + lane];
        float lv = 0.0f;
        int   hit = 0;
        // highest qualifying element within this float4
        if      (v.w <= tq) { lv = v.w; hit = 1; }
        else if (v.z <= tq) { lv = v.z; hit = 1; }
        else if (v.y <= tq) { lv = v.y; hit = 1; }
        else if (v.x <= tq) { lv = v.x; hit = 1; }

        const unsigned long long m = __ballot(hit);
        if (m != 0ULL) {
            // lanes map to increasing indices: highest set lane = last index
            const int src = 63 - __builtin_clzll(m);
            const float val = __shfl(lv, src, 64);
            if (lane == 0) out[row] = expf(-(tq - val));
            return;
        }
    }

    // ---- Phase 2: rare fallback — scan elements 0..1791 with full ILP ----
    int   best_idx = -1;
    float best_val = 0.0f;
    #pragma unroll
    for (int c = 0; c < 7; ++c) {
        const float4 v   = rp[c * 64 + lane];
        const int    eix = c * 256 + lane * 4;
        // chunks increase in index; later hit legitimately overwrites earlier
        if      (v.w <= tq) { best_idx = eix + 3; best_val = v.w; }
        else if (v.z <= tq) { best_idx = eix + 2; best_val = v.z; }
        else if (v.y <= tq) { best_idx = eix + 1; best_val = v.y; }
        else if (v.x <= tq) { best_idx = eix + 0; best_val = v.x; }
    }

    // Wave64 pair-reduction: keep the (idx, val) with the larger idx.
    #pragma unroll
    for (int off = 32; off > 0; off >>= 1) {
        const int   oi = __shfl_down(best_idx, off);
        const float ov = __shfl_down(best_val, off);
        if (oi > best_idx) { best_idx = oi; best_val = ov; }
    }

    if (lane == 0) {
        out[row] = (best_idx >= 0) ? expf(-(tq - best_val)) : 0.0f;
    }
}

extern "C" void kernel_launch(void* const* d_in, const int* in_sizes, int n_in,
                              void* d_out, int out_size, void* d_ws, size_t ws_size,
                              hipStream_t stream)
{
    // setup_inputs order: src(0), dst(1), t(2), x_pad_simu(3), t_pad(4).
    // Only t and t_pad feed the output.
    const float* t     = (const float*)d_in[2];
    const float* t_pad = (const float*)d_in[4];
    float*       out   = (float*)d_out;

    markov_last_event_kernel<<<dim3(N_Q / ROWS_PER_BLOCK), dim3(256), 0, stream>>>(
        t, t_pad, out);
}

// Round 5
// 307.300 us; speedup vs baseline: 1.1738x; 1.0128x over previous
//
#include <hip/hip_runtime.h>
#include <math.h>

// Problem constants (match reference file)
#define N_Q  32768
#define LEN  2048
#define ROWS_PER_BLOCK 4   // 4 waves of 64 lanes per 256-thread block

// Two-phase backward search, one wave (64 lanes) per row.
// Phase 1: probe the LAST 64 elements (1 dword/lane, coalesced 256 B/wave).
//   For uniform data P[no hit] = E[(1-t)^64] = 1/65 ~ 1.5%; otherwise the
//   highest hit lane (64-bit ballot) holds the last qualifying index.
// Phase 2 (1.5% of rows, wave-uniform branch): full 8-chunk float4 scan with
//   max-index shuffle reduction (re-reads the probed 256 B; L1/L2-hot).
// Expected HBM traffic ~12 MB vs 256 MB full read.
__global__ __launch_bounds__(256) void markov_last_event_kernel(
    const float* __restrict__ t,
    const float* __restrict__ t_pad,
    float* __restrict__ out)
{
    const int wave = threadIdx.x >> 6;   // 0..3
    const int lane = threadIdx.x & 63;   // 0..63
    const int row  = blockIdx.x * ROWS_PER_BLOCK + wave;

    const float tq = t[row];
    const float* rowp = t_pad + (size_t)row * LEN;

    // ---- Phase 1: last 64 elements (indices 1984..2047), 1 dword/lane ----
    {
        const float v = rowp[(LEN - 64) + lane];
        const unsigned long long m = __ballot(v <= tq);
        if (m != 0ULL) {
            // lanes map to increasing indices: highest set lane = last index
            const int src = 63 - __builtin_clzll(m);
            const float val = __shfl(v, src, 64);
            if (lane == 0) out[row] = expf(-(tq - val));
            return;
        }
    }

    // ---- Phase 2: rare fallback — full-row scan with full ILP ----
    const float4* rp = reinterpret_cast<const float4*>(rowp);
    int   best_idx = -1;
    float best_val = 0.0f;
    #pragma unroll
    for (int c = 0; c < 8; ++c) {
        const float4 v   = rp[c * 64 + lane];
        const int    eix = c * 256 + lane * 4;
        // chunks increase in index; later hit legitimately overwrites earlier
        if      (v.w <= tq) { best_idx = eix + 3; best_val = v.w; }
        else if (v.z <= tq) { best_idx = eix + 2; best_val = v.z; }
        else if (v.y <= tq) { best_idx = eix + 1; best_val = v.y; }
        else if (v.x <= tq) { best_idx = eix + 0; best_val = v.x; }
    }

    // Wave64 pair-reduction: keep the (idx, val) with the larger idx.
    #pragma unroll
    for (int off = 32; off > 0; off >>= 1) {
        const int   oi = __shfl_down(best_idx, off);
        const float ov = __shfl_down(best_val, off);
        if (oi > best_idx) { best_idx = oi; best_val = ov; }
    }

    if (lane == 0) {
        out[row] = (best_idx >= 0) ? expf(-(tq - best_val)) : 0.0f;
    }
}

extern "C" void kernel_launch(void* const* d_in, const int* in_sizes, int n_in,
                              void* d_out, int out_size, void* d_ws, size_t ws_size,
                              hipStream_t stream)
{
    // setup_inputs order: src(0), dst(1), t(2), x_pad_simu(3), t_pad(4).
    // Only t and t_pad feed the output.
    const float* t     = (const float*)d_in[2];
    const float* t_pad = (const float*)d_in[4];
    float*       out   = (float*)d_out;

    markov_last_event_kernel<<<dim3(N_Q / ROWS_PER_BLOCK), dim3(256), 0, stream>>>(
        t, t_pad, out);
}